// Round 4
// baseline (4686.045 us; speedup 1.0000x reference)
//
#include <hip/hip_runtime.h>
#include <hip/hip_bf16.h>
#include <stdint.h>

// Problem constants (fixed shapes)
#define E_ 8
#define H_ 2048
#define I_ 4096
#define T_ 1024
#define K_ 2
#define GS_ 128
#define NPAIR (T_ * K_)   // 2048
#define N1 (2 * I_)       // 8192 flat out-features for gemm1

// GEMM tile config (both gemms)
#define BM 64
#define BN 64
#define BK 64
#define NKH (H_ / BK)     // 32 k-iters gemm1
#define NKI (I_ / BK)     // 64 k-iters gemm2

// XOR-swizzled LDS: row stride 64 shorts (128 B), chunk = 8 shorts (16 B).
#define CH(r, c) ((((c) ^ ((r) & 7)) << 3))

typedef __attribute__((ext_vector_type(8))) short s16x8;   // 8 bf16
typedef __attribute__((ext_vector_type(4))) float f32x4;   // MFMA C/D

static __device__ __forceinline__ unsigned short f2bf(float f) {
    __hip_bfloat16 h = __float2bfloat16(f);
    return __builtin_bit_cast(unsigned short, h);
}
static __device__ __forceinline__ float bf2f(unsigned short u) {
    uint32_t v = ((uint32_t)u) << 16;
    return __builtin_bit_cast(float, v);
}
// pack two f32 -> bf16x2 (round-half-up via +0x8000)
static __device__ __forceinline__ uint32_t pk2(float lo16, float hi16) {
    uint32_t a = __builtin_bit_cast(uint32_t, lo16) + 0x8000u;
    uint32_t b = __builtin_bit_cast(uint32_t, hi16) + 0x8000u;
    return (a >> 16) | (b & 0xffff0000u);
}

// dequant 4 packed bytes (int4 of int32s, one byte per int) -> 8 bf16 chunk
static __device__ __forceinline__ void dq_chunk(int4 q, float sc, float zp,
                                                unsigned short* dst) {
    uint32_t r[4];
    int qa[4] = {q.x, q.y, q.z, q.w};
#pragma unroll
    for (int j = 0; j < 4; j++) {
        uint32_t byte = (uint32_t)qa[j] & 0xffu;
        float fh = (float)(byte >> 4) * sc + zp;   // even col (high nibble)
        float fl = (float)(byte & 15u) * sc + zp;  // odd col  (low nibble)
        r[j] = pk2(fh, fl);
    }
    *(uint4*)dst = make_uint4(r[0], r[1], r[2], r[3]);
}

// ---------------- x -> bf16 pre-pass ----------------
__global__ void x2bf_kernel(const float* __restrict__ x, unsigned short* __restrict__ xb) {
    int i = (blockIdx.x * 256 + threadIdx.x) * 8;
    float4 a = *(const float4*)(x + i);
    float4 b = *(const float4*)(x + i + 4);
    unsigned short t[8];
    t[0] = f2bf(a.x); t[1] = f2bf(a.y); t[2] = f2bf(a.z); t[3] = f2bf(a.w);
    t[4] = f2bf(b.x); t[5] = f2bf(b.y); t[6] = f2bf(b.z); t[7] = f2bf(b.w);
    *(s16x8*)(xb + i) = *(s16x8*)t;
}

// ---------------- zero output ----------------
__global__ void zero_f4(float4* p, int n4) {
    int i = blockIdx.x * blockDim.x + threadIdx.x;
    if (i < n4) p[i] = make_float4(0.f, 0.f, 0.f, 0.f);
}

// ---------------- router ----------------
__global__ void router_kernel(const int* __restrict__ ridx,
                              const float* __restrict__ rw,
                              int* __restrict__ seg,
                              int* __restrict__ ptok,
                              float* __restrict__ pw)
{
    __shared__ int cnt[E_];
    __shared__ int cur[E_];
    int tid = threadIdx.x;
    if (tid < E_) cnt[tid] = 0;
    __syncthreads();
    for (int p = tid; p < NPAIR; p += blockDim.x)
        atomicAdd(&cnt[ridx[p]], 1);
    __syncthreads();
    if (tid == 0) {
        int s = 0;
        for (int e = 0; e < E_; e++) { seg[e] = s; cur[e] = s; s += cnt[e]; }
        seg[E_] = s;
    }
    __syncthreads();
    for (int p = tid; p < NPAIR; p += blockDim.x) {
        int e = ridx[p];
        int pos = atomicAdd(&cur[e], 1);
        ptok[pos] = p >> 1;     // K_ == 2
        pw[pos] = rw[p];
    }
}

// ---------------- GEMM1 (flat): gu_out = x @ W_gu^T  [NPAIR][8192] bf16 ----------------
__global__ __launch_bounds__(256, 4) void gemm1_kernel(
    const unsigned short* __restrict__ xb,   // [T][H] bf16
    const int* __restrict__ gu_packed,       // [E][2I][H/2] (one byte per int32)
    const float* __restrict__ gu_scales,     // [E][2I][H/GS]
    const float* __restrict__ gu_zeros,
    const int* __restrict__ seg,
    const int* __restrict__ ptok,
    unsigned short* __restrict__ gu_out)     // [NPAIR][N1]
{
    const int e = blockIdx.z;
    const int seg0 = seg[e], seg1 = seg[e + 1];
    const int m0 = blockIdx.y * BM;
    if (seg0 + m0 >= seg1) return;
    const int n0 = blockIdx.x * BN;          // 0..N1-1

    __shared__ __align__(16) unsigned short sX[2][BM * 64];
    __shared__ __align__(16) unsigned short sW[2][BN * 64];

    const int tid = threadIdx.x;
    const int lane = tid & 63;
    const int wave = tid >> 6;
    const int wm = (wave >> 1) * 32;
    const int wn = (wave & 1) * 32;
    const int quad = lane >> 4;
    const int l16 = lane & 15;

    // staging: 4 threads/row, 2 chunks (16 shorts / 8 ints) each
    const int sr = tid >> 2;
    const int sc0 = (tid & 3) * 2;

    int slotX = seg0 + m0 + sr;
    if (slotX > NPAIR - 1) slotX = NPAIR - 1;
    const unsigned short* xrow = xb + (size_t)ptok[slotX] * H_ + (tid & 3) * 16;

    const int nr = n0 + sr;
    const int* wprow = gu_packed + ((size_t)e * N1 + nr) * (H_ / 2) + (tid & 3) * 8;
    const float* srow = gu_scales + ((size_t)e * N1 + nr) * (H_ / GS_);
    const float* zrow = gu_zeros  + ((size_t)e * N1 + nr) * (H_ / GS_);

    f32x4 acc[2][2];
#pragma unroll
    for (int mi = 0; mi < 2; mi++)
#pragma unroll
        for (int ni = 0; ni < 2; ni++)
            acc[mi][ni] = (f32x4){0.f, 0.f, 0.f, 0.f};

    s16x8 rX[2][2];
    int4 rW[2][2];
    float rs[2], rz[2];

#define G1_LOAD(k, s) { \
        const s16x8* xp = (const s16x8*)(xrow + (k)); \
        rX[s][0] = xp[0]; rX[s][1] = xp[1]; \
        const int4* wp = (const int4*)(wprow + ((k) >> 1)); \
        rW[s][0] = wp[0]; rW[s][1] = wp[1]; \
        rs[s] = srow[(k) >> 7]; rz[s] = zrow[(k) >> 7]; }

#define G1_STORE(s, b) { \
        *(s16x8*)&sX[b][(sr << 6) + CH(sr, sc0)]     = rX[s][0]; \
        *(s16x8*)&sX[b][(sr << 6) + CH(sr, sc0 + 1)] = rX[s][1]; \
        dq_chunk(rW[s][0], rs[s], rz[s], &sW[b][(sr << 6) + CH(sr, sc0)]); \
        dq_chunk(rW[s][1], rs[s], rz[s], &sW[b][(sr << 6) + CH(sr, sc0 + 1)]); }

    G1_LOAD(0, 0);
    G1_LOAD(BK, 1);
    G1_STORE(0, 0);
    __syncthreads();

    for (int j = 0; j < NKH; j++) {
        const int b = j & 1;
        if (j + 2 < NKH) G1_LOAD((j + 2) * BK, b);

#pragma unroll
        for (int ks = 0; ks < 2; ks++) {
            const int cb = ks * 4 + quad;
            s16x8 af[2], wf[2];
#pragma unroll
            for (int i = 0; i < 2; i++) {
                const int ra = wm + i * 16 + l16;
                af[i] = *(const s16x8*)&sX[b][(ra << 6) + CH(ra, cb)];
                const int rb = wn + i * 16 + l16;
                wf[i] = *(const s16x8*)&sW[b][(rb << 6) + CH(rb, cb)];
            }
#pragma unroll
            for (int mi = 0; mi < 2; mi++)
#pragma unroll
                for (int ni = 0; ni < 2; ni++)
                    acc[mi][ni] = __builtin_amdgcn_mfma_f32_16x16x32_bf16(af[mi], wf[ni], acc[mi][ni], 0, 0, 0);
        }

        if (j + 1 < NKH) { const int s = (j + 1) & 1; G1_STORE(s, s); }
        __syncthreads();
    }

#pragma unroll
    for (int mi = 0; mi < 2; mi++) {
#pragma unroll
        for (int rr = 0; rr < 4; rr++) {
            const int row = wm + mi * 16 + quad * 4 + rr;
            const int slot = seg0 + m0 + row;
            if (slot < seg1) {
#pragma unroll
                for (int ni = 0; ni < 2; ni++) {
                    const int col = n0 + wn + ni * 16 + l16;
                    gu_out[(size_t)slot * N1 + col] = f2bf(acc[mi][ni][rr]);
                }
            }
        }
    }
}

// ---------------- gelu(gate)*up in place (h -> gate half of gu) ----------------
__global__ void gelu_mul_kernel(unsigned short* __restrict__ gu) {
    int idx = blockIdx.x * 256 + threadIdx.x;   // one per 8 h-elements
    int s = idx >> 9;                           // I_/8 = 512 vecs per slot
    int c = (idx & 511) * 8;
    unsigned short* row = gu + (size_t)s * N1;
    s16x8 g8 = *(const s16x8*)(row + c);
    s16x8 u8 = *(const s16x8*)(row + I_ + c);
    unsigned short t[8];
#pragma unroll
    for (int j = 0; j < 8; j++) {
        float gv = bf2f((unsigned short)g8[j]);
        float uv = bf2f((unsigned short)u8[j]);
        float th = tanhf(0.7978845608028654f * (gv + 0.044715f * gv * gv * gv));
        t[j] = f2bf(0.5f * gv * (1.0f + th) * uv);
    }
    *(s16x8*)(row + c) = *(s16x8*)t;
}

// ---------------- GEMM2: out[tok] += coef * (h @ Wd^T) ----------------
__global__ __launch_bounds__(256, 4) void gemm2_kernel(
    const unsigned short* __restrict__ gu,     // h in gate half, row stride N1
    const int* __restrict__ dn_packed,         // [E][H][I/2] (one byte per int32)
    const float* __restrict__ dn_scales,       // [E][H][I/GS]
    const float* __restrict__ dn_zeros,
    const int* __restrict__ seg,
    const int* __restrict__ ptok,
    const float* __restrict__ pw,
    float* __restrict__ out)                   // [T][H]
{
    const int e = blockIdx.z;
    const int seg0 = seg[e], seg1 = seg[e + 1];
    const int m0 = blockIdx.y * BM;
    if (seg0 + m0 >= seg1) return;
    const int n0 = blockIdx.x * BN;

    __shared__ __align__(16) unsigned short sA[2][BM * 64];
    __shared__ __align__(16) unsigned short sW[2][BN * 64];

    const int tid = threadIdx.x;
    const int lane = tid & 63;
    const int wave = tid >> 6;
    const int wm = (wave >> 1) * 32;
    const int wn = (wave & 1) * 32;
    const int quad = lane >> 4;
    const int l16 = lane & 15;

    const int sr = tid >> 2;
    const int sc0 = (tid & 3) * 2;

    int slotA = seg0 + m0 + sr;
    if (slotA > NPAIR - 1) slotA = NPAIR - 1;
    const unsigned short* arow = gu + (size_t)slotA * N1 + (tid & 3) * 16;

    const int nr = n0 + sr;
    const int* wprow = dn_packed + ((size_t)e * H_ + nr) * (I_ / 2) + (tid & 3) * 8;
    const float* srow = dn_scales + ((size_t)e * H_ + nr) * (I_ / GS_);
    const float* zrow = dn_zeros  + ((size_t)e * H_ + nr) * (I_ / GS_);

    f32x4 acc[2][2];
#pragma unroll
    for (int mi = 0; mi < 2; mi++)
#pragma unroll
        for (int ni = 0; ni < 2; ni++)
            acc[mi][ni] = (f32x4){0.f, 0.f, 0.f, 0.f};

    s16x8 rA[2][2];
    int4 rW[2][2];
    float rs[2], rz[2];

#define G2_LOAD(k, s) { \
        const s16x8* ap = (const s16x8*)(arow + (k)); \
        rA[s][0] = ap[0]; rA[s][1] = ap[1]; \
        const int4* wp = (const int4*)(wprow + ((k) >> 1)); \
        rW[s][0] = wp[0]; rW[s][1] = wp[1]; \
        rs[s] = srow[(k) >> 7]; rz[s] = zrow[(k) >> 7]; }

#define G2_STORE(s, b) { \
        *(s16x8*)&sA[b][(sr << 6) + CH(sr, sc0)]     = rA[s][0]; \
        *(s16x8*)&sA[b][(sr << 6) + CH(sr, sc0 + 1)] = rA[s][1]; \
        dq_chunk(rW[s][0], rs[s], rz[s], &sW[b][(sr << 6) + CH(sr, sc0)]); \
        dq_chunk(rW[s][1], rs[s], rz[s], &sW[b][(sr << 6) + CH(sr, sc0 + 1)]); }

    G2_LOAD(0, 0);
    G2_LOAD(BK, 1);
    G2_STORE(0, 0);
    __syncthreads();

    for (int j = 0; j < NKI; j++) {
        const int b = j & 1;
        if (j + 2 < NKI) G2_LOAD((j + 2) * BK, b);

#pragma unroll
        for (int ks = 0; ks < 2; ks++) {
            const int cb = ks * 4 + quad;
            s16x8 af[2], wf[2];
#pragma unroll
            for (int i = 0; i < 2; i++) {
                const int ra = wm + i * 16 + l16;
                af[i] = *(const s16x8*)&sA[b][(ra << 6) + CH(ra, cb)];
                const int rb = wn + i * 16 + l16;
                wf[i] = *(const s16x8*)&sW[b][(rb << 6) + CH(rb, cb)];
            }
#pragma unroll
            for (int mi = 0; mi < 2; mi++)
#pragma unroll
                for (int ni = 0; ni < 2; ni++)
                    acc[mi][ni] = __builtin_amdgcn_mfma_f32_16x16x32_bf16(af[mi], wf[ni], acc[mi][ni], 0, 0, 0);
        }

        if (j + 1 < NKI) { const int s = (j + 1) & 1; G2_STORE(s, s); }
        __syncthreads();
    }

#pragma unroll
    for (int mi = 0; mi < 2; mi++) {
#pragma unroll
        for (int rr = 0; rr < 4; rr++) {
            const int row = wm + mi * 16 + quad * 4 + rr;
            const int slot = seg0 + m0 + row;
            if (slot < seg1) {
                const int tok = ptok[slot];
                const float cf = pw[slot];
#pragma unroll
                for (int ni = 0; ni < 2; ni++) {
                    const int col = n0 + wn + ni * 16 + l16;
                    atomicAdd(&out[(size_t)tok * H_ + col], cf * acc[mi][ni][rr]);
                }
            }
        }
    }
}

// ---------------- launch ----------------
extern "C" void kernel_launch(void* const* d_in, const int* in_sizes, int n_in,
                              void* d_out, int out_size, void* d_ws, size_t ws_size,
                              hipStream_t stream) {
    const float* x    = (const float*)d_in[0];
    const int*   gu_p = (const int*)d_in[1];     // uint8 in reference -> int32 on device
    const float* gu_s = (const float*)d_in[2];
    const float* gu_z = (const float*)d_in[3];
    const int*   dn_p = (const int*)d_in[4];
    const float* dn_s = (const float*)d_in[5];
    const float* dn_z = (const float*)d_in[6];
    const int*   ridx = (const int*)d_in[7];
    const float* rw   = (const float*)d_in[8];

    char* ws = (char*)d_ws;
    int*            seg   = (int*)ws;                               // 16 ints
    int*            ptok  = (int*)(ws + 256);                       // 2048 ints
    float*          pw    = (float*)(ws + 256 + NPAIR * 4);         // 2048 floats
    unsigned short* gu    = (unsigned short*)(ws + 32768);          // 2048 x 8192 bf16 = 32 MB
    unsigned short* xb    = (unsigned short*)(ws + 32768 + (size_t)NPAIR * N1 * 2);  // 4 MB

    float* out = (float*)d_out;

    x2bf_kernel<<<T_ * H_ / (256 * 8), 256, 0, stream>>>(x, xb);
    zero_f4<<<(T_ * H_ / 4 + 255) / 256, 256, 0, stream>>>((float4*)out, T_ * H_ / 4);
    router_kernel<<<1, 256, 0, stream>>>(ridx, rw, seg, ptok, pw);
    gemm1_kernel<<<dim3(N1 / BN, NPAIR / BM, E_), 256, 0, stream>>>(
        xb, gu_p, gu_s, gu_z, seg, ptok, gu);
    gelu_mul_kernel<<<NPAIR * (I_ / 8) / 256, 256, 0, stream>>>(gu);
    gemm2_kernel<<<dim3(H_ / BN, NPAIR / BM, E_), 256, 0, stream>>>(
        gu, dn_p, dn_s, dn_z, seg, ptok, pw, out);
}

// Round 5
// 736.117 us; speedup vs baseline: 6.3659x; 6.3659x over previous
//
#include <hip/hip_runtime.h>
#include <hip/hip_bf16.h>
#include <stdint.h>

// Problem constants (fixed shapes)
#define E_ 8
#define H_ 2048
#define I_ 4096
#define T_ 1024
#define K_ 2
#define GS_ 128
#define NPAIR (T_ * K_)   // 2048
#define N1 (2 * I_)       // 8192 flat out-features for gemm1

// GEMM tile config (both gemms)
#define BM 64
#define BN 64
#define BK 64
#define NKH (H_ / BK)     // 32 k-iters gemm1 (even)
#define NKI (I_ / BK)     // 64 k-iters gemm2 (even)

// XOR-swizzled LDS: row stride 64 shorts (128 B), chunk = 8 shorts (16 B).
#define CH(r, c) ((((c) ^ ((r) & 7)) << 3))

typedef __attribute__((ext_vector_type(8))) short s16x8;   // 8 bf16
typedef __attribute__((ext_vector_type(4))) float f32x4;   // MFMA C/D

static __device__ __forceinline__ unsigned short f2bf(float f) {
    __hip_bfloat16 h = __float2bfloat16(f);
    return __builtin_bit_cast(unsigned short, h);
}
static __device__ __forceinline__ float bf2f(unsigned short u) {
    uint32_t v = ((uint32_t)u) << 16;
    return __builtin_bit_cast(float, v);
}
// pack two f32 -> bf16x2 (round-half-up via +0x8000)
static __device__ __forceinline__ uint32_t pk2(float lo16, float hi16) {
    uint32_t a = __builtin_bit_cast(uint32_t, lo16) + 0x8000u;
    uint32_t b = __builtin_bit_cast(uint32_t, hi16) + 0x8000u;
    return (a >> 16) | (b & 0xffff0000u);
}

// dequant 4 packed bytes (int4 of int32s, one byte per int) -> 8 bf16 chunk
static __device__ __forceinline__ void dq_chunk(int4 q, float sc, float zp,
                                                unsigned short* dst) {
    uint32_t r[4];
    int qa[4] = {q.x, q.y, q.z, q.w};
#pragma unroll
    for (int j = 0; j < 4; j++) {
        uint32_t byte = (uint32_t)qa[j] & 0xffu;
        float fh = (float)(byte >> 4) * sc + zp;   // even col (high nibble)
        float fl = (float)(byte & 15u) * sc + zp;  // odd col  (low nibble)
        r[j] = pk2(fh, fl);
    }
    *(uint4*)dst = make_uint4(r[0], r[1], r[2], r[3]);
}

// ---------------- x -> bf16 pre-pass ----------------
__global__ void x2bf_kernel(const float* __restrict__ x, unsigned short* __restrict__ xb) {
    int i = (blockIdx.x * 256 + threadIdx.x) * 8;
    float4 a = *(const float4*)(x + i);
    float4 b = *(const float4*)(x + i + 4);
    unsigned short t[8];
    t[0] = f2bf(a.x); t[1] = f2bf(a.y); t[2] = f2bf(a.z); t[3] = f2bf(a.w);
    t[4] = f2bf(b.x); t[5] = f2bf(b.y); t[6] = f2bf(b.z); t[7] = f2bf(b.w);
    *(s16x8*)(xb + i) = *(s16x8*)t;
}

// ---------------- zero output ----------------
__global__ void zero_f4(float4* p, int n4) {
    int i = blockIdx.x * blockDim.x + threadIdx.x;
    if (i < n4) p[i] = make_float4(0.f, 0.f, 0.f, 0.f);
}

// ---------------- router ----------------
__global__ void router_kernel(const int* __restrict__ ridx,
                              const float* __restrict__ rw,
                              int* __restrict__ seg,
                              int* __restrict__ ptok,
                              float* __restrict__ pw)
{
    __shared__ int cnt[E_];
    __shared__ int cur[E_];
    int tid = threadIdx.x;
    if (tid < E_) cnt[tid] = 0;
    __syncthreads();
    for (int p = tid; p < NPAIR; p += blockDim.x)
        atomicAdd(&cnt[ridx[p]], 1);
    __syncthreads();
    if (tid == 0) {
        int s = 0;
        for (int e = 0; e < E_; e++) { seg[e] = s; cur[e] = s; s += cnt[e]; }
        seg[E_] = s;
    }
    __syncthreads();
    for (int p = tid; p < NPAIR; p += blockDim.x) {
        int e = ridx[p];
        int pos = atomicAdd(&cur[e], 1);
        ptok[pos] = p >> 1;     // K_ == 2
        pw[pos] = rw[p];
    }
}

// ---------------- GEMM1 (flat): gu_out = x @ W_gu^T  [NPAIR][8192] bf16 ----------------
__global__ __launch_bounds__(256, 4) void gemm1_kernel(
    const unsigned short* __restrict__ xb,   // [T][H] bf16
    const int* __restrict__ gu_packed,       // [E][2I][H/2] (one byte per int32)
    const float* __restrict__ gu_scales,     // [E][2I][H/GS]
    const float* __restrict__ gu_zeros,
    const int* __restrict__ seg,
    const int* __restrict__ ptok,
    unsigned short* __restrict__ gu_out)     // [NPAIR][N1]
{
    const int e = blockIdx.z;
    const int seg0 = seg[e], seg1 = seg[e + 1];
    const int m0 = blockIdx.y * BM;
    if (seg0 + m0 >= seg1) return;
    const int n0 = blockIdx.x * BN;          // 0..N1-1

    __shared__ __align__(16) unsigned short sX[2][BM * 64];
    __shared__ __align__(16) unsigned short sW[2][BN * 64];

    const int tid = threadIdx.x;
    const int lane = tid & 63;
    const int wave = tid >> 6;
    const int wm = (wave >> 1) * 32;
    const int wn = (wave & 1) * 32;
    const int quad = lane >> 4;
    const int l16 = lane & 15;

    // staging: 4 threads/row, 2 chunks (16 shorts / 8 ints) each
    const int sr = tid >> 2;
    const int sc0 = (tid & 3) * 2;

    int slotX = seg0 + m0 + sr;
    if (slotX > NPAIR - 1) slotX = NPAIR - 1;
    const unsigned short* xrow = xb + (size_t)ptok[slotX] * H_ + (tid & 3) * 16;

    const int nr = n0 + sr;
    const int* wprow = gu_packed + ((size_t)e * N1 + nr) * (H_ / 2) + (tid & 3) * 8;
    const float* srow = gu_scales + ((size_t)e * N1 + nr) * (H_ / GS_);
    const float* zrow = gu_zeros  + ((size_t)e * N1 + nr) * (H_ / GS_);

    f32x4 acc[2][2];
#pragma unroll
    for (int mi = 0; mi < 2; mi++)
#pragma unroll
        for (int ni = 0; ni < 2; ni++)
            acc[mi][ni] = (f32x4){0.f, 0.f, 0.f, 0.f};

    // two explicit register sets — all indices compile-time (NO dynamic array idx)
    s16x8 rXa0, rXa1, rXb0, rXb1;
    int4  rWa0, rWa1, rWb0, rWb1;
    float rsa, rza, rsb, rzb;

#define G1_LOAD_A(k) { \
        const s16x8* xp = (const s16x8*)(xrow + (k)); \
        rXa0 = xp[0]; rXa1 = xp[1]; \
        const int4* wp = (const int4*)(wprow + ((k) >> 1)); \
        rWa0 = wp[0]; rWa1 = wp[1]; \
        rsa = srow[(k) >> 7]; rza = zrow[(k) >> 7]; }
#define G1_LOAD_B(k) { \
        const s16x8* xp = (const s16x8*)(xrow + (k)); \
        rXb0 = xp[0]; rXb1 = xp[1]; \
        const int4* wp = (const int4*)(wprow + ((k) >> 1)); \
        rWb0 = wp[0]; rWb1 = wp[1]; \
        rsb = srow[(k) >> 7]; rzb = zrow[(k) >> 7]; }
#define G1_STORE_A(buf) { \
        *(s16x8*)&sX[buf][(sr << 6) + CH(sr, sc0)]     = rXa0; \
        *(s16x8*)&sX[buf][(sr << 6) + CH(sr, sc0 + 1)] = rXa1; \
        dq_chunk(rWa0, rsa, rza, &sW[buf][(sr << 6) + CH(sr, sc0)]); \
        dq_chunk(rWa1, rsa, rza, &sW[buf][(sr << 6) + CH(sr, sc0 + 1)]); }
#define G1_STORE_B(buf) { \
        *(s16x8*)&sX[buf][(sr << 6) + CH(sr, sc0)]     = rXb0; \
        *(s16x8*)&sX[buf][(sr << 6) + CH(sr, sc0 + 1)] = rXb1; \
        dq_chunk(rWb0, rsb, rzb, &sW[buf][(sr << 6) + CH(sr, sc0)]); \
        dq_chunk(rWb1, rsb, rzb, &sW[buf][(sr << 6) + CH(sr, sc0 + 1)]); }
#define G1_MFMA(buf) { \
        _Pragma("unroll") \
        for (int ks = 0; ks < 2; ks++) { \
            const int cb = ks * 4 + quad; \
            s16x8 af[2], wf[2]; \
            _Pragma("unroll") \
            for (int i = 0; i < 2; i++) { \
                const int ra = wm + i * 16 + l16; \
                af[i] = *(const s16x8*)&sX[buf][(ra << 6) + CH(ra, cb)]; \
                const int rb = wn + i * 16 + l16; \
                wf[i] = *(const s16x8*)&sW[buf][(rb << 6) + CH(rb, cb)]; \
            } \
            _Pragma("unroll") \
            for (int mi = 0; mi < 2; mi++) \
                _Pragma("unroll") \
                for (int ni = 0; ni < 2; ni++) \
                    acc[mi][ni] = __builtin_amdgcn_mfma_f32_16x16x32_bf16(af[mi], wf[ni], acc[mi][ni], 0, 0, 0); \
        } }

    G1_LOAD_A(0);
    G1_LOAD_B(BK);
    G1_STORE_A(0);
    __syncthreads();

    for (int j = 0; j < NKH; j += 2) {
        // even phase: compute LDS0 (tile j), prefetch tile j+2 -> A, stage B (tile j+1) -> LDS1
        if (j + 2 < NKH) G1_LOAD_A((j + 2) * BK);
        G1_MFMA(0);
        G1_STORE_B(1);                 // j+1 <= NKH-1 always (NKH even)
        __syncthreads();
        // odd phase: compute LDS1 (tile j+1), prefetch tile j+3 -> B, stage A (tile j+2) -> LDS0
        if (j + 3 < NKH) G1_LOAD_B((j + 3) * BK);
        G1_MFMA(1);
        if (j + 2 < NKH) G1_STORE_A(0);
        __syncthreads();
    }

#pragma unroll
    for (int mi = 0; mi < 2; mi++) {
#pragma unroll
        for (int rr = 0; rr < 4; rr++) {
            const int row = wm + mi * 16 + quad * 4 + rr;
            const int slot = seg0 + m0 + row;
            if (slot < seg1) {
#pragma unroll
                for (int ni = 0; ni < 2; ni++) {
                    const int col = n0 + wn + ni * 16 + l16;
                    gu_out[(size_t)slot * N1 + col] = f2bf(acc[mi][ni][rr]);
                }
            }
        }
    }
}

// ---------------- gelu(gate)*up in place (h -> gate half of gu) ----------------
__global__ void gelu_mul_kernel(unsigned short* __restrict__ gu) {
    int idx = blockIdx.x * 256 + threadIdx.x;   // one per 8 h-elements
    int s = idx >> 9;                           // I_/8 = 512 vecs per slot
    int c = (idx & 511) * 8;
    unsigned short* row = gu + (size_t)s * N1;
    s16x8 g8 = *(const s16x8*)(row + c);
    s16x8 u8 = *(const s16x8*)(row + I_ + c);
    unsigned short t[8];
#pragma unroll
    for (int j = 0; j < 8; j++) {
        float gv = bf2f((unsigned short)g8[j]);
        float uv = bf2f((unsigned short)u8[j]);
        float th = tanhf(0.7978845608028654f * (gv + 0.044715f * gv * gv * gv));
        t[j] = f2bf(0.5f * gv * (1.0f + th) * uv);
    }
    *(s16x8*)(row + c) = *(s16x8*)t;
}

// ---------------- GEMM2: out[tok] += coef * (h @ Wd^T) ----------------
__global__ __launch_bounds__(256, 4) void gemm2_kernel(
    const unsigned short* __restrict__ gu,     // h in gate half, row stride N1
    const int* __restrict__ dn_packed,         // [E][H][I/2] (one byte per int32)
    const float* __restrict__ dn_scales,       // [E][H][I/GS]
    const float* __restrict__ dn_zeros,
    const int* __restrict__ seg,
    const int* __restrict__ ptok,
    const float* __restrict__ pw,
    float* __restrict__ out)                   // [T][H]
{
    const int e = blockIdx.z;
    const int seg0 = seg[e], seg1 = seg[e + 1];
    const int m0 = blockIdx.y * BM;
    if (seg0 + m0 >= seg1) return;
    const int n0 = blockIdx.x * BN;

    __shared__ __align__(16) unsigned short sA[2][BM * 64];
    __shared__ __align__(16) unsigned short sW[2][BN * 64];

    const int tid = threadIdx.x;
    const int lane = tid & 63;
    const int wave = tid >> 6;
    const int wm = (wave >> 1) * 32;
    const int wn = (wave & 1) * 32;
    const int quad = lane >> 4;
    const int l16 = lane & 15;

    const int sr = tid >> 2;
    const int sc0 = (tid & 3) * 2;

    int slotA = seg0 + m0 + sr;
    if (slotA > NPAIR - 1) slotA = NPAIR - 1;
    const unsigned short* arow = gu + (size_t)slotA * N1 + (tid & 3) * 16;

    const int nr = n0 + sr;
    const int* wprow = dn_packed + ((size_t)e * H_ + nr) * (I_ / 2) + (tid & 3) * 8;
    const float* srow = dn_scales + ((size_t)e * H_ + nr) * (I_ / GS_);
    const float* zrow = dn_zeros  + ((size_t)e * H_ + nr) * (I_ / GS_);

    f32x4 acc[2][2];
#pragma unroll
    for (int mi = 0; mi < 2; mi++)
#pragma unroll
        for (int ni = 0; ni < 2; ni++)
            acc[mi][ni] = (f32x4){0.f, 0.f, 0.f, 0.f};

    s16x8 rAa0, rAa1, rAb0, rAb1;
    int4  rWa0, rWa1, rWb0, rWb1;
    float rsa, rza, rsb, rzb;

#define G2_LOAD_A(k) { \
        const s16x8* ap = (const s16x8*)(arow + (k)); \
        rAa0 = ap[0]; rAa1 = ap[1]; \
        const int4* wp = (const int4*)(wprow + ((k) >> 1)); \
        rWa0 = wp[0]; rWa1 = wp[1]; \
        rsa = srow[(k) >> 7]; rza = zrow[(k) >> 7]; }
#define G2_LOAD_B(k) { \
        const s16x8* ap = (const s16x8*)(arow + (k)); \
        rAb0 = ap[0]; rAb1 = ap[1]; \
        const int4* wp = (const int4*)(wprow + ((k) >> 1)); \
        rWb0 = wp[0]; rWb1 = wp[1]; \
        rsb = srow[(k) >> 7]; rzb = zrow[(k) >> 7]; }
#define G2_STORE_A(buf) { \
        *(s16x8*)&sA[buf][(sr << 6) + CH(sr, sc0)]     = rAa0; \
        *(s16x8*)&sA[buf][(sr << 6) + CH(sr, sc0 + 1)] = rAa1; \
        dq_chunk(rWa0, rsa, rza, &sW[buf][(sr << 6) + CH(sr, sc0)]); \
        dq_chunk(rWa1, rsa, rza, &sW[buf][(sr << 6) + CH(sr, sc0 + 1)]); }
#define G2_STORE_B(buf) { \
        *(s16x8*)&sA[buf][(sr << 6) + CH(sr, sc0)]     = rAb0; \
        *(s16x8*)&sA[buf][(sr << 6) + CH(sr, sc0 + 1)] = rAb1; \
        dq_chunk(rWb0, rsb, rzb, &sW[buf][(sr << 6) + CH(sr, sc0)]); \
        dq_chunk(rWb1, rsb, rzb, &sW[buf][(sr << 6) + CH(sr, sc0 + 1)]); }
#define G2_MFMA(buf) { \
        _Pragma("unroll") \
        for (int ks = 0; ks < 2; ks++) { \
            const int cb = ks * 4 + quad; \
            s16x8 af[2], wf[2]; \
            _Pragma("unroll") \
            for (int i = 0; i < 2; i++) { \
                const int ra = wm + i * 16 + l16; \
                af[i] = *(const s16x8*)&sA[buf][(ra << 6) + CH(ra, cb)]; \
                const int rb = wn + i * 16 + l16; \
                wf[i] = *(const s16x8*)&sW[buf][(rb << 6) + CH(rb, cb)]; \
            } \
            _Pragma("unroll") \
            for (int mi = 0; mi < 2; mi++) \
                _Pragma("unroll") \
                for (int ni = 0; ni < 2; ni++) \
                    acc[mi][ni] = __builtin_amdgcn_mfma_f32_16x16x32_bf16(af[mi], wf[ni], acc[mi][ni], 0, 0, 0); \
        } }

    G2_LOAD_A(0);
    G2_LOAD_B(BK);
    G2_STORE_A(0);
    __syncthreads();

    for (int j = 0; j < NKI; j += 2) {
        if (j + 2 < NKI) G2_LOAD_A((j + 2) * BK);
        G2_MFMA(0);
        G2_STORE_B(1);
        __syncthreads();
        if (j + 3 < NKI) G2_LOAD_B((j + 3) * BK);
        G2_MFMA(1);
        if (j + 2 < NKI) G2_STORE_A(0);
        __syncthreads();
    }

#pragma unroll
    for (int mi = 0; mi < 2; mi++) {
#pragma unroll
        for (int rr = 0; rr < 4; rr++) {
            const int row = wm + mi * 16 + quad * 4 + rr;
            const int slot = seg0 + m0 + row;
            if (slot < seg1) {
                const int tok = ptok[slot];
                const float cf = pw[slot];
#pragma unroll
                for (int ni = 0; ni < 2; ni++) {
                    const int col = n0 + wn + ni * 16 + l16;
                    atomicAdd(&out[(size_t)tok * H_ + col], cf * acc[mi][ni][rr]);
                }
            }
        }
    }
}

// ---------------- launch ----------------
extern "C" void kernel_launch(void* const* d_in, const int* in_sizes, int n_in,
                              void* d_out, int out_size, void* d_ws, size_t ws_size,
                              hipStream_t stream) {
    const float* x    = (const float*)d_in[0];
    const int*   gu_p = (const int*)d_in[1];     // uint8 in reference -> int32 on device
    const float* gu_s = (const float*)d_in[2];
    const float* gu_z = (const float*)d_in[3];
    const int*   dn_p = (const int*)d_in[4];
    const float* dn_s = (const float*)d_in[5];
    const float* dn_z = (const float*)d_in[6];
    const int*   ridx = (const int*)d_in[7];
    const float* rw   = (const float*)d_in[8];

    char* ws = (char*)d_ws;
    int*            seg   = (int*)ws;                               // 16 ints
    int*            ptok  = (int*)(ws + 256);                       // 2048 ints
    float*          pw    = (float*)(ws + 256 + NPAIR * 4);         // 2048 floats
    unsigned short* gu    = (unsigned short*)(ws + 32768);          // 2048 x 8192 bf16 = 32 MB
    unsigned short* xb    = (unsigned short*)(ws + 32768 + (size_t)NPAIR * N1 * 2);  // 4 MB

    float* out = (float*)d_out;

    x2bf_kernel<<<T_ * H_ / (256 * 8), 256, 0, stream>>>(x, xb);
    zero_f4<<<(T_ * H_ / 4 + 255) / 256, 256, 0, stream>>>((float4*)out, T_ * H_ / 4);
    router_kernel<<<1, 256, 0, stream>>>(ridx, rw, seg, ptok, pw);
    gemm1_kernel<<<dim3(N1 / BN, NPAIR / BM, E_), 256, 0, stream>>>(
        xb, gu_p, gu_s, gu_z, seg, ptok, gu);
    gelu_mul_kernel<<<NPAIR * (I_ / 8) / 256, 256, 0, stream>>>(gu);
    gemm2_kernel<<<dim3(H_ / BN, NPAIR / BM, E_), 256, 0, stream>>>(
        gu, dn_p, dn_s, dn_z, seg, ptok, pw, out);
}